// Round 20
// baseline (116.657 us; speedup 1.0000x reference)
//
#include <hip/hip_runtime.h>
#include <hip/hip_bf16.h>

#define BB 2
#define SS 2048
#define DD 1024
#define HH 16
#define DHH 64

typedef __attribute__((ext_vector_type(8))) __bf16 bf16x8;
typedef __attribute__((ext_vector_type(4))) float f32x4;
typedef __attribute__((ext_vector_type(16))) float f32x16;
typedef __attribute__((ext_vector_type(4))) int i32x4;
typedef __attribute__((ext_vector_type(4))) unsigned int u32x4;

#define MFMA16 __builtin_amdgcn_mfma_f32_16x16x32_bf16
#define MFMA32 __builtin_amdgcn_mfma_f32_32x32x16_bf16

__device__ __forceinline__ unsigned short f2b(float f) {
  __hip_bfloat16 h = __float2bfloat16(f);
  unsigned short u;
  __builtin_memcpy(&u, &h, 2);
  return u;
}

__device__ __forceinline__ float b2f(unsigned short u) {
  unsigned int x = ((unsigned int)u) << 16;
  float f;
  __builtin_memcpy(&f, &x, 4);
  return f;
}

__device__ __forceinline__ float exp2_fast(float x) {
  float r;
  asm("v_exp_f32 %0, %1" : "=v"(r) : "v"(x));
  return r;
}

__device__ __forceinline__ unsigned int cvtpk_bf16(float lo_, float hi_) {
  unsigned int r;
  asm("v_cvt_pk_bf16_f32 %0, %1, %2" : "=v"(r) : "v"(lo_), "v"(hi_));
  return r;
}

// async global -> LDS, 16B per lane. LDS dest = wave-uniform base + lane*16.
__device__ __forceinline__ void gl_lds16(const void* g, void* l) {
  __builtin_amdgcn_global_load_lds((const __attribute__((address_space(1))) void*)g,
                                   (__attribute__((address_space(3))) void*)l, 16, 0, 0);
}

// ---------------- fused prep: cast x + transpose-cast all weights ----------------
__global__ __launch_bounds__(256) void k_prep(const float* __restrict__ x,
                                              const float* __restrict__ Wq,
                                              const float* __restrict__ Wk,
                                              const float* __restrict__ Wv,
                                              const float* __restrict__ Wo,
                                              unsigned short* __restrict__ xb,
                                              unsigned short* __restrict__ wqkvt,
                                              unsigned short* __restrict__ wot) {
  int blk = blockIdx.x;
  if (blk < 4096) {
    int i = blk * 256 + threadIdx.x;
    float4 v = ((const float4*)x)[i];
    ushort4 o;
    o.x = f2b(v.x); o.y = f2b(v.y); o.z = f2b(v.z); o.w = f2b(v.w);
    ((ushort4*)xb)[i] = o;
    return;
  }
  __shared__ float t[32][33];
  const float* im;
  unsigned short* om;
  int R, C, c0, r0;
  if (blk < 7168) {
    int bi2 = blk - 4096;
    int z = bi2 >> 6, rem = bi2 & 63;
    im = (z < 16 ? Wq : (z < 32 ? Wk : Wv)) + (size_t)(z & 15) * DD * DHH;
    om = wqkvt + (size_t)z * DD * DHH;
    R = DD; C = DHH;
    c0 = (rem & 1) * 32; r0 = (rem >> 1) * 32;
  } else {
    int bi2 = blk - 7168;
    im = Wo; om = wot;
    R = DD; C = DD;
    c0 = (bi2 & 31) * 32; r0 = (bi2 >> 5) * 32;
  }
  int tx = threadIdx.x & 31, ty = threadIdx.x >> 5;
#pragma unroll
  for (int rr = ty; rr < 32; rr += 8)
    t[rr][tx] = im[(size_t)(r0 + rr) * C + c0 + tx];
  __syncthreads();
#pragma unroll
  for (int rr = ty; rr < 32; rr += 8)
    om[(size_t)(c0 + rr) * R + r0 + tx] = f2b(t[tx][rr]);
}

// ---------------- QKV GEMM: 128x128 tile, BK=32, depth-2 counted-vmcnt ----------------
// acc[4][4]/wave (reads halve per MFMA vs 128x64). 3 bufs x 16KB = 48KB -> 3 blocks/CU.
// Swizzle for 64B rows: key = (row>>1)&3 (8 distinct bank-groups over 8 rows);
// pre-swizzled global source + XOR'd read col (both-sides involution).
__global__ __launch_bounds__(256, 3) void k_qkv(const unsigned short* __restrict__ A,
                                                const unsigned short* __restrict__ Wt,
                                                const float* __restrict__ bq,
                                                const float* __restrict__ bk,
                                                const float* __restrict__ bv,
                                                unsigned short* __restrict__ Qb,
                                                unsigned short* __restrict__ Kb,
                                                unsigned short* __restrict__ Vtb) {
  __shared__ __align__(16) unsigned short SMEM[3 * 8192];  // 49152 B; per buf: A 8KB + B 8KB
  int tid = threadIdx.x;
  int w = tid >> 6, l = tid & 63, lr = l & 15, lg = l >> 4;
  int wr = w >> 1, wc = w & 1;
  int col0 = blockIdx.x * 128, row0 = blockIdx.y * 128;
  int sel = col0 >> 10;
  bool vsel = (sel == 2);
  const float* biasp = sel == 0 ? bq : (sel == 1 ? bk : bv);
  unsigned short* outp = sel == 0 ? Qb : Kb;
  float qscale = sel == 0 ? 0.18033688011112042f : 1.0f;  // 0.125 * log2(e)

  // staging lane map: row16 = l>>2 (16 rows per instr), chunk c4 = l&3 (4 x 16B per 64B row)
  int r16 = l >> 2, c4 = l & 3;
  int cg = c4 ^ ((r16 >> 1) & 3);  // pre-swizzled global 16B chunk
  const unsigned short* Ab = A + (size_t)(row0 + w * 32 + r16) * DD + cg * 8;
  const unsigned short* Bb = Wt + (size_t)(col0 + w * 32 + r16) * DD + cg * 8;
  const int swr = ((lr >> 1) & 3) << 4;  // read-side XOR (bytes)

  f32x4 zero = {0.f, 0.f, 0.f, 0.f};
  f32x4 acc[4][4];
#pragma unroll
  for (int m = 0; m < 4; m++)
#pragma unroll
    for (int n = 0; n < 4; n++) acc[m][n] = zero;

#define QKV_STAGE(T) do { \
    unsigned short* buf_ = SMEM + ((T) % 3) * 8192; \
    int k0_ = (T) * 32; \
    _Pragma("unroll") \
    for (int c = 0; c < 2; c++) \
      gl_lds16(Ab + (size_t)c * 16 * DD + k0_, (char*)buf_ + (w * 32 + c * 16) * 64); \
    _Pragma("unroll") \
    for (int c = 0; c < 2; c++) \
      gl_lds16(Bb + (size_t)c * 16 * DD + k0_, (char*)(buf_ + 4096) + (w * 32 + c * 16) * 64); \
  } while (0)

#define QKV_COMPUTE(T) do { \
    const char* As_ = (const char*)(SMEM + ((T) % 3) * 8192); \
    const char* Bs_ = As_ + 8192; \
    int co_ = (lg * 16) ^ swr; \
    bf16x8 af[4], bfr[4]; \
    _Pragma("unroll") \
    for (int m = 0; m < 4; m++) \
      af[m] = *(const bf16x8*)(As_ + (wr * 64 + m * 16 + lr) * 64 + co_); \
    _Pragma("unroll") \
    for (int n = 0; n < 4; n++) \
      bfr[n] = *(const bf16x8*)(Bs_ + (wc * 64 + n * 16 + lr) * 64 + co_); \
    if (!vsel) { \
      _Pragma("unroll") \
      for (int m = 0; m < 4; m++) \
        _Pragma("unroll") \
        for (int n = 0; n < 4; n++) \
          acc[m][n] = MFMA16(af[m], bfr[n], acc[m][n], 0, 0, 0); \
    } else { \
      _Pragma("unroll") \
      for (int m = 0; m < 4; m++) \
        _Pragma("unroll") \
        for (int n = 0; n < 4; n++) \
          acc[m][n] = MFMA16(bfr[n], af[m], acc[m][n], 0, 0, 0); \
    } \
  } while (0)

  QKV_STAGE(0);
  QKV_STAGE(1);
  for (int t = 0; t < 31; t++) {
    asm volatile("s_waitcnt vmcnt(4) lgkmcnt(0)" ::: "memory");
    __builtin_amdgcn_s_barrier();
    if (t + 2 < 32) QKV_STAGE(t + 2);
    QKV_COMPUTE(t);
  }
  asm volatile("s_waitcnt vmcnt(0) lgkmcnt(0)" ::: "memory");
  __builtin_amdgcn_s_barrier();
  QKV_COMPUTE(31);
#undef QKV_STAGE
#undef QKV_COMPUTE

  __syncthreads();  // all reads of SMEM done; reuse as Ts[128][136] (34816 B)
  unsigned short* Ts = SMEM;
  if (!vsel) {
    // acc: D[row=s_local][col=c_local]
#pragma unroll
    for (int n = 0; n < 4; n++) {
      int cl = wc * 64 + n * 16 + lr;
      float bias = biasp[(col0 + cl) & 1023];
#pragma unroll
      for (int m = 0; m < 4; m++) {
#pragma unroll
        for (int j = 0; j < 4; j++) {
          int sl = wr * 64 + m * 16 + lg * 4 + j;
          Ts[sl * 136 + cl] = f2b((acc[m][n][j] + bias) * qscale);
        }
      }
    }
    __syncthreads();
    int trow = tid >> 4, tc = tid & 15;
#pragma unroll
    for (int pass = 0; pass < 8; pass++) {
      int sl = pass * 16 + trow;
      int c0l = tc * 8;
      i32x4 v = *(const i32x4*)&Ts[sl * 136 + c0l];
      int c = col0 + c0l;
      int hh = (c >> 6) & 15, d = c & 63;
      int row = row0 + sl;
      int b = row >> 11, s = row & 2047;
      *(i32x4*)(outp + ((size_t)(b * HH + hh) * SS + s) * DHH + d) = v;
    }
  } else {
    // acc: D[row=c_local(d)][col=s_local]
#pragma unroll
    for (int n = 0; n < 4; n++) {
#pragma unroll
      for (int j = 0; j < 4; j++) {
        int cl = wc * 64 + n * 16 + lg * 4 + j;
        float bias = bv[((col0 & 1023) + cl) & 1023];
#pragma unroll
        for (int m = 0; m < 4; m++) {
          int sl = wr * 64 + m * 16 + lr;
          Ts[cl * 136 + sl] = f2b(acc[m][n][j] + bias);
        }
      }
    }
    __syncthreads();
    int trow = tid >> 4, tc = tid & 15;
    int b = row0 >> 11, s0 = row0 & 2047;
#pragma unroll
    for (int pass = 0; pass < 8; pass++) {
      int cl = pass * 16 + trow;
      int s8 = tc * 8;
      i32x4 v = *(const i32x4*)&Ts[cl * 136 + s8];
      int cg2 = (col0 & 1023) + cl;
      *(i32x4*)(Vtb + (size_t)(b * 1024 + cg2) * SS + s0 + s8) = v;
    }
  }
}

// ---------------- output projection: 64x64 tile, counted-vmcnt + T2 swizzle ----------------
__global__ __launch_bounds__(256, 3) void k_proj(const unsigned short* __restrict__ A,
                                                 const unsigned short* __restrict__ Wt,
                                                 const float* __restrict__ bo,
                                                 float* __restrict__ out) {
  __shared__ __align__(16) unsigned short SMEM[3 * 8192];  // 49152 B
  int tid = threadIdx.x;
  int w = tid >> 6, l = tid & 63, lr = l & 15, lg = l >> 4;
  int col0 = blockIdx.x * 64, row0 = blockIdx.y * 64;

  int r8 = l >> 3, c8 = l & 7;
  const unsigned short* Ab = A + (size_t)(row0 + w * 16 + r8) * DD + (c8 ^ r8) * 8;
  const unsigned short* Bb = Wt + (size_t)(col0 + w * 16 + r8) * DD + (c8 ^ r8) * 8;
  const int swr = (lr & 7) << 4;

  f32x4 zero = {0.f, 0.f, 0.f, 0.f};
  f32x4 acc[4];
#pragma unroll
  for (int n = 0; n < 4; n++) acc[n] = zero;

#define PROJ_STAGE(T) do { \
    unsigned short* buf_ = SMEM + ((T) % 3) * 8192; \
    int k0_ = (T) * 64; \
    _Pragma("unroll") \
    for (int c = 0; c < 2; c++) { \
      gl_lds16(Ab + (size_t)c * 8 * DD + k0_, (char*)buf_ + (w * 16 + c * 8) * 128); \
      gl_lds16(Bb + (size_t)c * 8 * DD + k0_, (char*)(buf_ + 4096) + (w * 16 + c * 8) * 128); \
    } \
  } while (0)

#define PROJ_COMPUTE(T) do { \
    const char* As_ = (const char*)(SMEM + ((T) % 3) * 8192); \
    const char* Bs_ = As_ + 8192; \
    _Pragma("unroll") \
    for (int kk = 0; kk < 2; kk++) { \
      int co_ = (kk * 64 + lg * 16) ^ swr; \
      bf16x8 af = *(const bf16x8*)(As_ + (w * 16 + lr) * 128 + co_); \
      bf16x8 bfr[4]; \
      _Pragma("unroll") \
      for (int n = 0; n < 4; n++) \
        bfr[n] = *(const bf16x8*)(Bs_ + (n * 16 + lr) * 128 + co_); \
      _Pragma("unroll") \
      for (int n = 0; n < 4; n++) \
        acc[n] = MFMA16(af, bfr[n], acc[n], 0, 0, 0); \
    } \
  } while (0)

  PROJ_STAGE(0);
  PROJ_STAGE(1);
  for (int t = 0; t < 15; t++) {
    asm volatile("s_waitcnt vmcnt(4) lgkmcnt(0)" ::: "memory");
    __builtin_amdgcn_s_barrier();
    if (t + 2 < 16) PROJ_STAGE(t + 2);
    PROJ_COMPUTE(t);
  }
  asm volatile("s_waitcnt vmcnt(0) lgkmcnt(0)" ::: "memory");
  __builtin_amdgcn_s_barrier();
  PROJ_COMPUTE(15);
#undef PROJ_STAGE
#undef PROJ_COMPUTE

#pragma unroll
  for (int n = 0; n < 4; n++) {
    int c = col0 + n * 16 + lr;
    float bias = bo[c];
#pragma unroll
    for (int j = 0; j < 4; j++) {
      int row = row0 + w * 16 + lg * 4 + j;
      out[(size_t)row * DD + c] = acc[n][j] + bias;
    }
  }
}

// ---------------- flash attention, KV-split=2 (R19-proven) ----------------
#define QT 128
#define KVB 64

__global__ __launch_bounds__(256, 4) void k_attn(const unsigned short* __restrict__ Q,
                                                 const unsigned short* __restrict__ K,
                                                 const unsigned short* __restrict__ Vt,
                                                 unsigned short* __restrict__ Opart,
                                                 float* __restrict__ lse) {
  __shared__ __align__(16) char sm[32768];

  int tid = threadIdx.x;
  int w = tid >> 6, lane = tid & 63;
  int q32 = lane & 31, hi = lane >> 5;
  int r8 = lane >> 3, c8 = lane & 7;
  int cg = c8 ^ r8;

  int n = blockIdx.x;
  int bh = ((n & 7) << 2) | ((n >> 3) & 3);
  int rest = n >> 5;
  int q0 = (rest & 15) * QT;
  int chunk = rest >> 4;
  int kvbase = chunk * (SS / 2);

  const unsigned short* Qm = Q + (size_t)bh * SS * DHH;
  const unsigned short* Km = K + (size_t)bh * SS * DHH;
  const unsigned short* Vm = Vt + (size_t)bh * DHH * SS;

  bf16x8 qf[4];
  {
    const unsigned short* qrow = Qm + (size_t)(q0 + w * 32 + q32) * DHH + hi * 8;
#pragma unroll
    for (int ks = 0; ks < 4; ks++)
      qf[ks] = *(const bf16x8*)(qrow + ks * 16);
  }

#pragma unroll
  for (int c = 0; c < 2; c++) {
    int rr = w * 16 + c * 8 + r8;
    gl_lds16(Km + (size_t)(kvbase + rr) * DHH + cg * 8, sm + (w * 16 + c * 8) * 128);
    gl_lds16(Vm + (size_t)rr * SS + kvbase + cg * 8, sm + 16384 + (w * 16 + c * 8) * 128);
  }
  __syncthreads();

  const f32x16 FZERO = {};
  f32x16 oacc0 = FZERO, oacc1 = FZERO;
  float m_ = -1e30f, l_ = 0.f;
  const int swq = (q32 & 7) << 4;

  for (int t = 0; t < SS / 2 / KVB; t++) {
    const char* Kc = sm + (t & 1) * 8192;
    const char* Vc = sm + 16384 + (t & 1) * 8192;

    if (t + 1 < SS / 2 / KVB) {
      int kv0 = kvbase + (t + 1) * KVB;
      char* kd = sm + ((t + 1) & 1) * 8192;
      char* vd = sm + 16384 + ((t + 1) & 1) * 8192;
#pragma unroll
      for (int c = 0; c < 2; c++) {
        int rr = w * 16 + c * 8 + r8;
        gl_lds16(Km + (size_t)(kv0 + rr) * DHH + cg * 8, kd + (w * 16 + c * 8) * 128);
        gl_lds16(Vm + (size_t)rr * SS + kv0 + cg * 8, vd + (w * 16 + c * 8) * 128);
      }
    }

    // ---- QK^T: mfma(K, Q) -> D[kv][q]; first ks reads FZERO as C ----
    f32x16 p0, p1;
    __builtin_amdgcn_s_setprio(1);
    {
      int co = (hi * 16) ^ swq;
      bf16x8 kf0 = *(const bf16x8*)(Kc + q32 * 128 + co);
      bf16x8 kf1 = *(const bf16x8*)(Kc + (32 + q32) * 128 + co);
      p0 = MFMA32(kf0, qf[0], FZERO, 0, 0, 0);
      p1 = MFMA32(kf1, qf[0], FZERO, 0, 0, 0);
    }
#pragma unroll
    for (int ks = 1; ks < 4; ks++) {
      int co = (ks * 32 + hi * 16) ^ swq;
      bf16x8 kf0 = *(const bf16x8*)(Kc + q32 * 128 + co);
      bf16x8 kf1 = *(const bf16x8*)(Kc + (32 + q32) * 128 + co);
      p0 = MFMA32(kf0, qf[ks], p0, 0, 0, 0);
      p1 = MFMA32(kf1, qf[ks], p1, 0, 0, 0);
    }
    __builtin_amdgcn_s_setprio(0);

    // ---- online softmax (lane-local rows, defer-max THR=8, tree reduce) ----
    float t8[8];
#pragma unroll
    for (int r = 0; r < 8; r++)
      t8[r] = fmaxf(fmaxf(p0[r], p0[r + 8]), fmaxf(p1[r], p1[r + 8]));
#pragma unroll
    for (int r = 0; r < 4; r++) t8[r] = fmaxf(t8[r], t8[r + 4]);
    float tmax = fmaxf(fmaxf(t8[0], t8[1]), fmaxf(t8[2], t8[3]));
    tmax = fmaxf(tmax, __shfl_xor(tmax, 32));

    if (__any(tmax > m_ + 8.0f)) {
      float nm = fmaxf(m_, tmax);
      float al = exp2_fast(m_ - nm);
      m_ = nm; l_ *= al;
#pragma unroll
      for (int r = 0; r < 16; r++) { oacc0[r] *= al; oacc1[r] *= al; }
    }

#pragma unroll
    for (int r = 0; r < 16; r++) p0[r] = exp2_fast(p0[r] - m_);
#pragma unroll
    for (int r = 0; r < 16; r++) p1[r] = exp2_fast(p1[r] - m_);
    float s8[8];
#pragma unroll
    for (int r = 0; r < 8; r++) s8[r] = (p0[r] + p0[r + 8]) + (p1[r] + p1[r + 8]);
#pragma unroll
    for (int r = 0; r < 4; r++) s8[r] += s8[r + 4];
    l_ += ((s8[0] + s8[1]) + (s8[2] + s8[3]));

    // ---- P -> bf16 A-frag (permlane32_swap half-exchange) + PV interleaved ----
    __builtin_amdgcn_s_setprio(1);
    u32x4 pa;
#define MKPA(PB, u) do { \
    unsigned int a0 = cvtpk_bf16(PB[8*(u)+0], PB[8*(u)+1]); \
    unsigned int a1 = cvtpk_bf16(PB[8*(u)+2], PB[8*(u)+3]); \
    unsigned int b0 = cvtpk_bf16(PB[8*(u)+4], PB[8*(u)+5]); \
    unsigned int b1 = cvtpk_bf16(PB[8*(u)+6], PB[8*(u)+7]); \
    asm("v_permlane32_swap_b32 %0, %1" : "+v"(a0), "+v"(b0)); \
    asm("v_permlane32_swap_b32 %0, %1" : "+v"(a1), "+v"(b1)); \
    pa[0] = a0; pa[1] = a1; pa[2] = b0; pa[3] = b1; \
  } while (0)
#define PVSTEP(s) do { \
    bf16x8 pf = *(bf16x8*)&pa; \
    bf16x8 vf0 = *(const bf16x8*)(Vc + q32 * 128 + (((s) * 32 + hi * 16) ^ swq)); \
    bf16x8 vf1 = *(const bf16x8*)(Vc + (32 + q32) * 128 + (((s) * 32 + hi * 16) ^ swq)); \
    oacc0 = MFMA32(vf0, pf, oacc0, 0, 0, 0); \
    oacc1 = MFMA32(vf1, pf, oacc1, 0, 0, 0); \
  } while (0)
    MKPA(p0, 0); PVSTEP(0);
    MKPA(p0, 1); PVSTEP(1);
    MKPA(p1, 0); PVSTEP(2);
    MKPA(p1, 1); PVSTEP(3);
#undef MKPA
#undef PVSTEP
    __builtin_amdgcn_s_setprio(0);

    __syncthreads();
  }

  // ---- epilogue: per-chunk normalize, lse, LDS transpose, coalesced store ----
  l_ += __shfl_xor(l_, 32);
  float invl = 1.0f / l_;
  float lsev = m_ + __log2f(l_);
  __syncthreads();
  unsigned short* Os = (unsigned short*)sm;
  int rowq = w * 32 + q32;
#pragma unroll
  for (int r = 0; r < 16; r++) {
    int d = (r & 3) + 8 * (r >> 2) + 4 * hi;
    Os[rowq * 72 + d] = f2b(oacc0[r] * invl);
    Os[rowq * 72 + 32 + d] = f2b(oacc1[r] * invl);
  }
  if (hi == 0) lse[((size_t)chunk * 32 + bh) * SS + q0 + rowq] = lsev;
  __syncthreads();
#pragma unroll
  for (int i = 0; i < 4; i++) {
    int ci = tid + i * 256;
    int r = ci >> 3, c = ci & 7;
    i32x4 v = *(const i32x4*)&Os[r * 72 + c * 8];
    *(i32x4*)(Opart + (((size_t)chunk * 32 + bh) * SS + q0 + r) * DHH + c * 8) = v;
  }
}

// ---------------- combine: Ocat = softmax-weighted merge of 2 chunks ----------------
__global__ __launch_bounds__(256) void k_comb(const unsigned short* __restrict__ Opart,
                                              const float* __restrict__ lse,
                                              unsigned short* __restrict__ Ocat) {
  int g = blockIdx.x * 256 + threadIdx.x;  // 0..524287
  int row = g >> 3;                        // bh*2048 + q
  int d8 = (g & 7) * 8;
  int bh = row >> 11, q = row & 2047;
  int bi = bh >> 4, h = bh & 15;
  float e0 = lse[row], e1 = lse[BB * HH * SS + row];
  float mx = fmaxf(e0, e1);
  float w0 = exp2_fast(e0 - mx), w1 = exp2_fast(e1 - mx);
  float inv = 1.0f / (w0 + w1);
  w0 *= inv; w1 *= inv;
  const unsigned short* P0 = Opart + (size_t)row * DHH + d8;
  const unsigned short* P1 = P0 + (size_t)BB * HH * SS * DHH;
  ushort4 a0 = *(const ushort4*)P0, a1 = *(const ushort4*)(P0 + 4);
  ushort4 b0 = *(const ushort4*)P1, b1 = *(const ushort4*)(P1 + 4);
  ushort4 o0, o1;
  o0.x = f2b(w0 * b2f(a0.x) + w1 * b2f(b0.x));
  o0.y = f2b(w0 * b2f(a0.y) + w1 * b2f(b0.y));
  o0.z = f2b(w0 * b2f(a0.z) + w1 * b2f(b0.z));
  o0.w = f2b(w0 * b2f(a0.w) + w1 * b2f(b0.w));
  o1.x = f2b(w0 * b2f(a1.x) + w1 * b2f(b1.x));
  o1.y = f2b(w0 * b2f(a1.y) + w1 * b2f(b1.y));
  o1.z = f2b(w0 * b2f(a1.z) + w1 * b2f(b1.z));
  o1.w = f2b(w0 * b2f(a1.w) + w1 * b2f(b1.w));
  unsigned short* op = Ocat + ((size_t)(bi * SS + q)) * DD + h * DHH + d8;
  *(ushort4*)op = o0;
  *(ushort4*)(op + 4) = o1;
}

extern "C" void kernel_launch(void* const* d_in, const int* in_sizes, int n_in,
                              void* d_out, int out_size, void* d_ws, size_t ws_size,
                              hipStream_t stream) {
  const float* x  = (const float*)d_in[0];
  const float* Wq = (const float*)d_in[1];
  const float* bq = (const float*)d_in[2];
  const float* Wk = (const float*)d_in[3];
  const float* bk = (const float*)d_in[4];
  const float* Wv = (const float*)d_in[5];
  const float* bv = (const float*)d_in[6];
  const float* Wo = (const float*)d_in[7];
  const float* bo = (const float*)d_in[8];
  float* out = (float*)d_out;

  char* ws = (char*)d_ws;
  unsigned short* xb    = (unsigned short*)(ws);                       // 8 MB
  unsigned short* wqkvt = (unsigned short*)(ws + (size_t)(8u  << 20)); // 6 MB
  unsigned short* wot   = (unsigned short*)(ws + (size_t)(14u << 20)); // 2 MB
  unsigned short* Qb    = (unsigned short*)(ws + (size_t)(16u << 20)); // 8 MB
  unsigned short* Kb    = (unsigned short*)(ws + (size_t)(24u << 20)); // 8 MB
  unsigned short* Vt    = (unsigned short*)(ws + (size_t)(32u << 20)); // 8 MB
  unsigned short* Ocat  = (unsigned short*)(ws + (size_t)(40u << 20)); // 8 MB
  unsigned short* Opart = (unsigned short*)(ws + (size_t)(48u << 20)); // 16 MB
  float*          lse   = (float*)(ws + (size_t)(64u << 20));          // 0.5 MB

  k_prep<<<8192, 256, 0, stream>>>(x, Wq, Wk, Wv, Wo, xb, wqkvt, wot);
  k_qkv<<<dim3(3 * DD / 128, BB * SS / 128), 256, 0, stream>>>(xb, wqkvt, bq, bk, bv, Qb, Kb, Vt);
  k_attn<<<dim3(1024), 256, 0, stream>>>(Qb, Kb, Vt, Opart, lse);
  k_comb<<<dim3(2048), 256, 0, stream>>>(Opart, lse, Ocat);
  k_proj<<<dim3(DD / 64, BB * SS / 64), 256, 0, stream>>>(Ocat, wot, bo, out);
}

// Round 21
// 113.027 us; speedup vs baseline: 1.0321x; 1.0321x over previous
//
#include <hip/hip_runtime.h>
#include <hip/hip_bf16.h>

#define BB 2
#define SS 2048
#define DD 1024
#define HH 16
#define DHH 64

typedef __attribute__((ext_vector_type(8))) __bf16 bf16x8;
typedef __attribute__((ext_vector_type(4))) float f32x4;
typedef __attribute__((ext_vector_type(16))) float f32x16;
typedef __attribute__((ext_vector_type(4))) int i32x4;
typedef __attribute__((ext_vector_type(4))) unsigned int u32x4;

#define MFMA16 __builtin_amdgcn_mfma_f32_16x16x32_bf16
#define MFMA32 __builtin_amdgcn_mfma_f32_32x32x16_bf16

__device__ __forceinline__ unsigned short f2b(float f) {
  __hip_bfloat16 h = __float2bfloat16(f);
  unsigned short u;
  __builtin_memcpy(&u, &h, 2);
  return u;
}

__device__ __forceinline__ float b2f(unsigned short u) {
  unsigned int x = ((unsigned int)u) << 16;
  float f;
  __builtin_memcpy(&f, &x, 4);
  return f;
}

__device__ __forceinline__ float exp2_fast(float x) {
  float r;
  asm("v_exp_f32 %0, %1" : "=v"(r) : "v"(x));
  return r;
}

__device__ __forceinline__ unsigned int cvtpk_bf16(float lo_, float hi_) {
  unsigned int r;
  asm("v_cvt_pk_bf16_f32 %0, %1, %2" : "=v"(r) : "v"(lo_), "v"(hi_));
  return r;
}

// async global -> LDS, 16B per lane. LDS dest = wave-uniform base + lane*16.
__device__ __forceinline__ void gl_lds16(const void* g, void* l) {
  __builtin_amdgcn_global_load_lds((const __attribute__((address_space(1))) void*)g,
                                   (__attribute__((address_space(3))) void*)l, 16, 0, 0);
}

// ---------------- fused prep: cast x + transpose-cast all weights ----------------
__global__ __launch_bounds__(256) void k_prep(const float* __restrict__ x,
                                              const float* __restrict__ Wq,
                                              const float* __restrict__ Wk,
                                              const float* __restrict__ Wv,
                                              const float* __restrict__ Wo,
                                              unsigned short* __restrict__ xb,
                                              unsigned short* __restrict__ wqkvt,
                                              unsigned short* __restrict__ wot) {
  int blk = blockIdx.x;
  if (blk < 4096) {
    int i = blk * 256 + threadIdx.x;
    float4 v = ((const float4*)x)[i];
    ushort4 o;
    o.x = f2b(v.x); o.y = f2b(v.y); o.z = f2b(v.z); o.w = f2b(v.w);
    ((ushort4*)xb)[i] = o;
    return;
  }
  __shared__ float t[32][33];
  const float* im;
  unsigned short* om;
  int R, C, c0, r0;
  if (blk < 7168) {
    int bi2 = blk - 4096;
    int z = bi2 >> 6, rem = bi2 & 63;
    im = (z < 16 ? Wq : (z < 32 ? Wk : Wv)) + (size_t)(z & 15) * DD * DHH;
    om = wqkvt + (size_t)z * DD * DHH;
    R = DD; C = DHH;
    c0 = (rem & 1) * 32; r0 = (rem >> 1) * 32;
  } else {
    int bi2 = blk - 7168;
    im = Wo; om = wot;
    R = DD; C = DD;
    c0 = (bi2 & 31) * 32; r0 = (bi2 >> 5) * 32;
  }
  int tx = threadIdx.x & 31, ty = threadIdx.x >> 5;
#pragma unroll
  for (int rr = ty; rr < 32; rr += 8)
    t[rr][tx] = im[(size_t)(r0 + rr) * C + c0 + tx];
  __syncthreads();
#pragma unroll
  for (int rr = ty; rr < 32; rr += 8)
    om[(size_t)(c0 + rr) * R + r0 + tx] = f2b(t[tx][rr]);
}

// ---------------- QKV GEMM: 128x64 tile, counted-vmcnt + T2 XOR-swizzle ----------------
__global__ __launch_bounds__(256, 2) void k_qkv(const unsigned short* __restrict__ A,
                                                const unsigned short* __restrict__ Wt,
                                                const float* __restrict__ bq,
                                                const float* __restrict__ bk,
                                                const float* __restrict__ bv,
                                                unsigned short* __restrict__ Qb,
                                                unsigned short* __restrict__ Kb,
                                                unsigned short* __restrict__ Vtb) {
  __shared__ __align__(16) unsigned short SMEM[3 * 12288];  // 73728 B
  int tid = threadIdx.x;
  int w = tid >> 6, l = tid & 63, lr = l & 15, lg = l >> 4;
  int col0 = blockIdx.x * 64, row0 = blockIdx.y * 128;
  int sel = col0 >> 10;
  bool vsel = (sel == 2);
  const float* biasp = sel == 0 ? bq : (sel == 1 ? bk : bv);
  unsigned short* outp = sel == 0 ? Qb : Kb;
  float qscale = sel == 0 ? 0.18033688011112042f : 1.0f;  // 0.125 * log2(e)

  int r8 = l >> 3, c8 = l & 7;
  const unsigned short* Ab = A + (size_t)(row0 + w * 32 + r8) * DD + (c8 ^ r8) * 8;
  const unsigned short* Bb = Wt + (size_t)(col0 + w * 16 + r8) * DD + (c8 ^ r8) * 8;
  const int swr = (lr & 7) << 4;

  f32x4 zero = {0.f, 0.f, 0.f, 0.f};
  f32x4 acc[2][4];
#pragma unroll
  for (int m = 0; m < 2; m++)
#pragma unroll
    for (int n = 0; n < 4; n++) acc[m][n] = zero;

#define QKV_STAGE(T) do { \
    unsigned short* buf_ = SMEM + ((T) % 3) * 12288; \
    int k0_ = (T) * 64; \
    _Pragma("unroll") \
    for (int c = 0; c < 4; c++) \
      gl_lds16(Ab + (size_t)c * 8 * DD + k0_, (char*)buf_ + (w * 32 + c * 8) * 128); \
    _Pragma("unroll") \
    for (int c = 0; c < 2; c++) \
      gl_lds16(Bb + (size_t)c * 8 * DD + k0_, (char*)(buf_ + 8192) + (w * 16 + c * 8) * 128); \
  } while (0)

#define QKV_COMPUTE(T) do { \
    const char* As_ = (const char*)(SMEM + ((T) % 3) * 12288); \
    const char* Bs_ = As_ + 16384; \
    _Pragma("unroll") \
    for (int kk = 0; kk < 2; kk++) { \
      int co_ = (kk * 64 + lg * 16) ^ swr; \
      bf16x8 af[2], bfr[4]; \
      _Pragma("unroll") \
      for (int m = 0; m < 2; m++) \
        af[m] = *(const bf16x8*)(As_ + (w * 32 + m * 16 + lr) * 128 + co_); \
      _Pragma("unroll") \
      for (int n = 0; n < 4; n++) \
        bfr[n] = *(const bf16x8*)(Bs_ + (n * 16 + lr) * 128 + co_); \
      if (!vsel) { \
        _Pragma("unroll") \
        for (int m = 0; m < 2; m++) \
          _Pragma("unroll") \
          for (int n = 0; n < 4; n++) \
            acc[m][n] = MFMA16(af[m], bfr[n], acc[m][n], 0, 0, 0); \
      } else { \
        _Pragma("unroll") \
        for (int m = 0; m < 2; m++) \
          _Pragma("unroll") \
          for (int n = 0; n < 4; n++) \
            acc[m][n] = MFMA16(bfr[n], af[m], acc[m][n], 0, 0, 0); \
      } \
    } \
  } while (0)

  QKV_STAGE(0);
  QKV_STAGE(1);
  for (int t = 0; t < 15; t++) {
    asm volatile("s_waitcnt vmcnt(6) lgkmcnt(0)" ::: "memory");
    __builtin_amdgcn_s_barrier();
    if (t + 2 < 16) QKV_STAGE(t + 2);
    QKV_COMPUTE(t);
  }
  asm volatile("s_waitcnt vmcnt(0) lgkmcnt(0)" ::: "memory");
  __builtin_amdgcn_s_barrier();
  QKV_COMPUTE(15);
#undef QKV_STAGE
#undef QKV_COMPUTE

  __syncthreads();  // all reads of SMEM done; reuse as Ts
  unsigned short* Ts = SMEM;
  if (!vsel) {
#pragma unroll
    for (int n = 0; n < 4; n++) {
      int cl = n * 16 + lr;
      float bias = biasp[(col0 + cl) & 1023];
#pragma unroll
      for (int m = 0; m < 2; m++) {
#pragma unroll
        for (int j = 0; j < 4; j++) {
          int sl = w * 32 + m * 16 + lg * 4 + j;
          Ts[sl * 72 + cl] = f2b((acc[m][n][j] + bias) * qscale);
        }
      }
    }
    __syncthreads();
    int trow = tid >> 3, tc = tid & 7;
#pragma unroll
    for (int pass = 0; pass < 4; pass++) {
      int sl = pass * 32 + trow;
      int c0l = tc * 8;
      i32x4 v = *(const i32x4*)&Ts[sl * 72 + c0l];
      int c = col0 + c0l;
      int hh = (c >> 6) & 15, d = c & 63;
      int row = row0 + sl;
      int b = row >> 11, s = row & 2047;
      *(i32x4*)(outp + ((size_t)(b * HH + hh) * SS + s) * DHH + d) = v;
    }
  } else {
#pragma unroll
    for (int n = 0; n < 4; n++) {
#pragma unroll
      for (int j = 0; j < 4; j++) {
        int cl = n * 16 + lg * 4 + j;
        float bias = bv[((col0 & 1023) + cl) & 1023];
#pragma unroll
        for (int m = 0; m < 2; m++) {
          int sl = w * 32 + m * 16 + lr;
          Ts[cl * 136 + sl] = f2b(acc[m][n][j] + bias);
        }
      }
    }
    __syncthreads();
    int trow = tid >> 4, tc = tid & 15;
    int b = row0 >> 11, s0 = row0 & 2047;
#pragma unroll
    for (int pass = 0; pass < 4; pass++) {
      int cl = pass * 16 + trow;
      int s8 = tc * 8;
      i32x4 v = *(const i32x4*)&Ts[cl * 136 + s8];
      int cg = (col0 & 1023) + cl;
      *(i32x4*)(Vtb + (size_t)(b * 1024 + cg) * SS + s0 + s8) = v;
    }
  }
}

// ---------------- output projection: 64x64 tile, counted-vmcnt + T2 swizzle ----------------
__global__ __launch_bounds__(256, 3) void k_proj(const unsigned short* __restrict__ A,
                                                 const unsigned short* __restrict__ Wt,
                                                 const float* __restrict__ bo,
                                                 float* __restrict__ out) {
  __shared__ __align__(16) unsigned short SMEM[3 * 8192];  // 49152 B
  int tid = threadIdx.x;
  int w = tid >> 6, l = tid & 63, lr = l & 15, lg = l >> 4;
  int col0 = blockIdx.x * 64, row0 = blockIdx.y * 64;

  int r8 = l >> 3, c8 = l & 7;
  const unsigned short* Ab = A + (size_t)(row0 + w * 16 + r8) * DD + (c8 ^ r8) * 8;
  const unsigned short* Bb = Wt + (size_t)(col0 + w * 16 + r8) * DD + (c8 ^ r8) * 8;
  const int swr = (lr & 7) << 4;

  f32x4 zero = {0.f, 0.f, 0.f, 0.f};
  f32x4 acc[4];
#pragma unroll
  for (int n = 0; n < 4; n++) acc[n] = zero;

#define PROJ_STAGE(T) do { \
    unsigned short* buf_ = SMEM + ((T) % 3) * 8192; \
    int k0_ = (T) * 64; \
    _Pragma("unroll") \
    for (int c = 0; c < 2; c++) { \
      gl_lds16(Ab + (size_t)c * 8 * DD + k0_, (char*)buf_ + (w * 16 + c * 8) * 128); \
      gl_lds16(Bb + (size_t)c * 8 * DD + k0_, (char*)(buf_ + 4096) + (w * 16 + c * 8) * 128); \
    } \
  } while (0)

#define PROJ_COMPUTE(T) do { \
    const char* As_ = (const char*)(SMEM + ((T) % 3) * 8192); \
    const char* Bs_ = As_ + 8192; \
    _Pragma("unroll") \
    for (int kk = 0; kk < 2; kk++) { \
      int co_ = (kk * 64 + lg * 16) ^ swr; \
      bf16x8 af = *(const bf16x8*)(As_ + (w * 16 + lr) * 128 + co_); \
      bf16x8 bfr[4]; \
      _Pragma("unroll") \
      for (int n = 0; n < 4; n++) \
        bfr[n] = *(const bf16x8*)(Bs_ + (n * 16 + lr) * 128 + co_); \
      _Pragma("unroll") \
      for (int n = 0; n < 4; n++) \
        acc[n] = MFMA16(af, bfr[n], acc[n], 0, 0, 0); \
    } \
  } while (0)

  PROJ_STAGE(0);
  PROJ_STAGE(1);
  for (int t = 0; t < 15; t++) {
    asm volatile("s_waitcnt vmcnt(4) lgkmcnt(0)" ::: "memory");
    __builtin_amdgcn_s_barrier();
    if (t + 2 < 16) PROJ_STAGE(t + 2);
    PROJ_COMPUTE(t);
  }
  asm volatile("s_waitcnt vmcnt(0) lgkmcnt(0)" ::: "memory");
  __builtin_amdgcn_s_barrier();
  PROJ_COMPUTE(15);
#undef PROJ_STAGE
#undef PROJ_COMPUTE

#pragma unroll
  for (int n = 0; n < 4; n++) {
    int c = col0 + n * 16 + lr;
    float bias = bo[c];
#pragma unroll
    for (int j = 0; j < 4; j++) {
      int row = row0 + w * 16 + lg * 4 + j;
      out[(size_t)row * DD + c] = acc[n][j] + bias;
    }
  }
}

// ---------------- flash attention, KV-split=2 (R19-proven) ----------------
#define QT 128
#define KVB 64

__global__ __launch_bounds__(256, 4) void k_attn(const unsigned short* __restrict__ Q,
                                                 const unsigned short* __restrict__ K,
                                                 const unsigned short* __restrict__ Vt,
                                                 unsigned short* __restrict__ Opart,
                                                 float* __restrict__ lse) {
  __shared__ __align__(16) char sm[32768];

  int tid = threadIdx.x;
  int w = tid >> 6, lane = tid & 63;
  int q32 = lane & 31, hi = lane >> 5;
  int r8 = lane >> 3, c8 = lane & 7;
  int cg = c8 ^ r8;

  int n = blockIdx.x;
  int bh = ((n & 7) << 2) | ((n >> 3) & 3);
  int rest = n >> 5;
  int q0 = (rest & 15) * QT;
  int chunk = rest >> 4;
  int kvbase = chunk * (SS / 2);

  const unsigned short* Qm = Q + (size_t)bh * SS * DHH;
  const unsigned short* Km = K + (size_t)bh * SS * DHH;
  const unsigned short* Vm = Vt + (size_t)bh * DHH * SS;

  bf16x8 qf[4];
  {
    const unsigned short* qrow = Qm + (size_t)(q0 + w * 32 + q32) * DHH + hi * 8;
#pragma unroll
    for (int ks = 0; ks < 4; ks++)
      qf[ks] = *(const bf16x8*)(qrow + ks * 16);
  }

#pragma unroll
  for (int c = 0; c < 2; c++) {
    int rr = w * 16 + c * 8 + r8;
    gl_lds16(Km + (size_t)(kvbase + rr) * DHH + cg * 8, sm + (w * 16 + c * 8) * 128);
    gl_lds16(Vm + (size_t)rr * SS + kvbase + cg * 8, sm + 16384 + (w * 16 + c * 8) * 128);
  }
  __syncthreads();

  const f32x16 FZERO = {};
  f32x16 oacc0 = FZERO, oacc1 = FZERO;
  float m_ = -1e30f, l_ = 0.f;
  const int swq = (q32 & 7) << 4;

  for (int t = 0; t < SS / 2 / KVB; t++) {
    const char* Kc = sm + (t & 1) * 8192;
    const char* Vc = sm + 16384 + (t & 1) * 8192;

    if (t + 1 < SS / 2 / KVB) {
      int kv0 = kvbase + (t + 1) * KVB;
      char* kd = sm + ((t + 1) & 1) * 8192;
      char* vd = sm + 16384 + ((t + 1) & 1) * 8192;
#pragma unroll
      for (int c = 0; c < 2; c++) {
        int rr = w * 16 + c * 8 + r8;
        gl_lds16(Km + (size_t)(kv0 + rr) * DHH + cg * 8, kd + (w * 16 + c * 8) * 128);
        gl_lds16(Vm + (size_t)rr * SS + kv0 + cg * 8, vd + (w * 16 + c * 8) * 128);
      }
    }

    // ---- QK^T: mfma(K, Q) -> D[kv][q]; first ks reads FZERO as C ----
    f32x16 p0, p1;
    __builtin_amdgcn_s_setprio(1);
    {
      int co = (hi * 16) ^ swq;
      bf16x8 kf0 = *(const bf16x8*)(Kc + q32 * 128 + co);
      bf16x8 kf1 = *(const bf16x8*)(Kc + (32 + q32) * 128 + co);
      p0 = MFMA32(kf0, qf[0], FZERO, 0, 0, 0);
      p1 = MFMA32(kf1, qf[0], FZERO, 0, 0, 0);
    }
#pragma unroll
    for (int ks = 1; ks < 4; ks++) {
      int co = (ks * 32 + hi * 16) ^ swq;
      bf16x8 kf0 = *(const bf16x8*)(Kc + q32 * 128 + co);
      bf16x8 kf1 = *(const bf16x8*)(Kc + (32 + q32) * 128 + co);
      p0 = MFMA32(kf0, qf[ks], p0, 0, 0, 0);
      p1 = MFMA32(kf1, qf[ks], p1, 0, 0, 0);
    }
    __builtin_amdgcn_s_setprio(0);

    // ---- online softmax (lane-local rows, defer-max THR=8, tree reduce) ----
    float t8[8];
#pragma unroll
    for (int r = 0; r < 8; r++)
      t8[r] = fmaxf(fmaxf(p0[r], p0[r + 8]), fmaxf(p1[r], p1[r + 8]));
#pragma unroll
    for (int r = 0; r < 4; r++) t8[r] = fmaxf(t8[r], t8[r + 4]);
    float tmax = fmaxf(fmaxf(t8[0], t8[1]), fmaxf(t8[2], t8[3]));
    tmax = fmaxf(tmax, __shfl_xor(tmax, 32));

    if (__any(tmax > m_ + 8.0f)) {
      float nm = fmaxf(m_, tmax);
      float al = exp2_fast(m_ - nm);
      m_ = nm; l_ *= al;
#pragma unroll
      for (int r = 0; r < 16; r++) { oacc0[r] *= al; oacc1[r] *= al; }
    }

#pragma unroll
    for (int r = 0; r < 16; r++) p0[r] = exp2_fast(p0[r] - m_);
#pragma unroll
    for (int r = 0; r < 16; r++) p1[r] = exp2_fast(p1[r] - m_);
    float s8[8];
#pragma unroll
    for (int r = 0; r < 8; r++) s8[r] = (p0[r] + p0[r + 8]) + (p1[r] + p1[r + 8]);
#pragma unroll
    for (int r = 0; r < 4; r++) s8[r] += s8[r + 4];
    l_ += ((s8[0] + s8[1]) + (s8[2] + s8[3]));

    // ---- P -> bf16 A-frag (permlane32_swap half-exchange) + PV interleaved ----
    __builtin_amdgcn_s_setprio(1);
    u32x4 pa;
#define MKPA(PB, u) do { \
    unsigned int a0 = cvtpk_bf16(PB[8*(u)+0], PB[8*(u)+1]); \
    unsigned int a1 = cvtpk_bf16(PB[8*(u)+2], PB[8*(u)+3]); \
    unsigned int b0 = cvtpk_bf16(PB[8*(u)+4], PB[8*(u)+5]); \
    unsigned int b1 = cvtpk_bf16(PB[8*(u)+6], PB[8*(u)+7]); \
    asm("v_permlane32_swap_b32 %0, %1" : "+v"(a0), "+v"(b0)); \
    asm("v_permlane32_swap_b32 %0, %1" : "+v"(a1), "+v"(b1)); \
    pa[0] = a0; pa[1] = a1; pa[2] = b0; pa[3] = b1; \
  } while (0)
#define PVSTEP(s) do { \
    bf16x8 pf = *(bf16x8*)&pa; \
    bf16x8 vf0 = *(const bf16x8*)(Vc + q32 * 128 + (((s) * 32 + hi * 16) ^ swq)); \
    bf16x8 vf1 = *(const bf16x8*)(Vc + (32 + q32) * 128 + (((s) * 32 + hi * 16) ^ swq)); \
    oacc0 = MFMA32(vf0, pf, oacc0, 0, 0, 0); \
    oacc1 = MFMA32(vf1, pf, oacc1, 0, 0, 0); \
  } while (0)
    MKPA(p0, 0); PVSTEP(0);
    MKPA(p0, 1); PVSTEP(1);
    MKPA(p1, 0); PVSTEP(2);
    MKPA(p1, 1); PVSTEP(3);
#undef MKPA
#undef PVSTEP
    __builtin_amdgcn_s_setprio(0);

    __syncthreads();
  }

  // ---- epilogue: per-chunk normalize, lse, LDS transpose, coalesced store ----
  l_ += __shfl_xor(l_, 32);
  float invl = 1.0f / l_;
  float lsev = m_ + __log2f(l_);
  __syncthreads();
  unsigned short* Os = (unsigned short*)sm;
  int rowq = w * 32 + q32;
#pragma unroll
  for (int r = 0; r < 16; r++) {
    int d = (r & 3) + 8 * (r >> 2) + 4 * hi;
    Os[rowq * 72 + d] = f2b(oacc0[r] * invl);
    Os[rowq * 72 + 32 + d] = f2b(oacc1[r] * invl);
  }
  if (hi == 0) lse[((size_t)chunk * 32 + bh) * SS + q0 + rowq] = lsev;
  __syncthreads();
#pragma unroll
  for (int i = 0; i < 4; i++) {
    int ci = tid + i * 256;
    int r = ci >> 3, c = ci & 7;
    i32x4 v = *(const i32x4*)&Os[r * 72 + c * 8];
    *(i32x4*)(Opart + (((size_t)chunk * 32 + bh) * SS + q0 + r) * DHH + c * 8) = v;
  }
}

// ---------------- combine: Ocat = softmax-weighted merge of 2 chunks ----------------
__global__ __launch_bounds__(256) void k_comb(const unsigned short* __restrict__ Opart,
                                              const float* __restrict__ lse,
                                              unsigned short* __restrict__ Ocat) {
  int g = blockIdx.x * 256 + threadIdx.x;  // 0..524287
  int row = g >> 3;                        // bh*2048 + q
  int d8 = (g & 7) * 8;
  int bh = row >> 11, q = row & 2047;
  int bi = bh >> 4, h = bh & 15;
  float e0 = lse[row], e1 = lse[BB * HH * SS + row];
  float mx = fmaxf(e0, e1);
  float w0 = exp2_fast(e0 - mx), w1 = exp2_fast(e1 - mx);
  float inv = 1.0f / (w0 + w1);
  w0 *= inv; w1 *= inv;
  const unsigned short* P0 = Opart + (size_t)row * DHH + d8;
  const unsigned short* P1 = P0 + (size_t)BB * HH * SS * DHH;
  ushort4 a0 = *(const ushort4*)P0, a1 = *(const ushort4*)(P0 + 4);
  ushort4 b0 = *(const ushort4*)P1, b1 = *(const ushort4*)(P1 + 4);
  ushort4 o0, o1;
  o0.x = f2b(w0 * b2f(a0.x) + w1 * b2f(b0.x));
  o0.y = f2b(w0 * b2f(a0.y) + w1 * b2f(b0.y));
  o0.z = f2b(w0 * b2f(a0.z) + w1 * b2f(b0.z));
  o0.w = f2b(w0 * b2f(a0.w) + w1 * b2f(b0.w));
  o1.x = f2b(w0 * b2f(a1.x) + w1 * b2f(b1.x));
  o1.y = f2b(w0 * b2f(a1.y) + w1 * b2f(b1.y));
  o1.z = f2b(w0 * b2f(a1.z) + w1 * b2f(b1.z));
  o1.w = f2b(w0 * b2f(a1.w) + w1 * b2f(b1.w));
  unsigned short* op = Ocat + ((size_t)(bi * SS + q)) * DD + h * DHH + d8;
  *(ushort4*)op = o0;
  *(ushort4*)(op + 4) = o1;
}

extern "C" void kernel_launch(void* const* d_in, const int* in_sizes, int n_in,
                              void* d_out, int out_size, void* d_ws, size_t ws_size,
                              hipStream_t stream) {
  const float* x  = (const float*)d_in[0];
  const float* Wq = (const float*)d_in[1];
  const float* bq = (const float*)d_in[2];
  const float* Wk = (const float*)d_in[3];
  const float* bk = (const float*)d_in[4];
  const float* Wv = (const float*)d_in[5];
  const float* bv = (const float*)d_in[6];
  const float* Wo = (const float*)d_in[7];
  const float* bo = (const float*)d_in[8];
  float* out = (float*)d_out;

  char* ws = (char*)d_ws;
  unsigned short* xb    = (unsigned short*)(ws);                       // 8 MB
  unsigned short* wqkvt = (unsigned short*)(ws + (size_t)(8u  << 20)); // 6 MB
  unsigned short* wot   = (unsigned short*)(ws + (size_t)(14u << 20)); // 2 MB
  unsigned short* Qb    = (unsigned short*)(ws + (size_t)(16u << 20)); // 8 MB
  unsigned short* Kb    = (unsigned short*)(ws + (size_t)(24u << 20)); // 8 MB
  unsigned short* Vt    = (unsigned short*)(ws + (size_t)(32u << 20)); // 8 MB
  unsigned short* Ocat  = (unsigned short*)(ws + (size_t)(40u << 20)); // 8 MB
  unsigned short* Opart = (unsigned short*)(ws + (size_t)(48u << 20)); // 16 MB
  float*          lse   = (float*)(ws + (size_t)(64u << 20));          // 0.5 MB

  k_prep<<<8192, 256, 0, stream>>>(x, Wq, Wk, Wv, Wo, xb, wqkvt, wot);
  k_qkv<<<dim3(3 * DD / 64, BB * SS / 128), 256, 0, stream>>>(xb, wqkvt, bq, bk, bv, Qb, Kb, Vt);
  k_attn<<<dim3(1024), 256, 0, stream>>>(Qb, Kb, Vt, Opart, lse);
  k_comb<<<dim3(2048), 256, 0, stream>>>(Opart, lse, Ocat);
  k_proj<<<dim3(DD / 64, BB * SS / 64), 256, 0, stream>>>(Ocat, wot, bo, out);
}